// Round 9
// baseline (134.465 us; speedup 1.0000x reference)
//
#include <hip/hip_runtime.h>
#include <math.h>

#define B 2048
#define D 64
#define NC2 16          // j-chunks for the MFMA/LSE role

typedef float v2f  __attribute__((ext_vector_type(2)));
typedef short bf16x8 __attribute__((ext_vector_type(8)));
typedef float f32x4  __attribute__((ext_vector_type(4)));

static __device__ __forceinline__ float exp2fast(float x) { return __builtin_amdgcn_exp2f(x); }
static __device__ __forceinline__ float log2fast(float x) { return __builtin_amdgcn_logf(x); }
static __device__ __forceinline__ unsigned short f2bf(float x) {
    unsigned u = __float_as_uint(x);
    u += 0x7fff + ((u >> 16) & 1);          // RNE; inputs are finite
    return (unsigned short)(u >> 16);
}

// ---------------------------------------------------------------------------
// Kernel 1: per-(j,d) constants (log2 units):  lp2 = h*z^2 + g*z + q
//   h = -0.5*log2e*exp(-lv), g = -2*mu*h, q = mu^2*h + c,
//   c = -0.5*log2e*(lv + ln 2pi)
// Outputs: pack4 (fp32, main role), Zx/Wt (bf16 MFMA operands), QQ[j]=sum_d q,
// acc zeroed, kl block-reduced -> 1 atomic.
// ---------------------------------------------------------------------------
__global__ __launch_bounds__(256) void k_pre(
    const float* __restrict__ kl, const float* __restrict__ zm,
    const float* __restrict__ zlv, const float* __restrict__ zs,
    float4* __restrict__ pack4, unsigned short* __restrict__ Zx,
    unsigned short* __restrict__ Wt, float* __restrict__ QQ,
    float* __restrict__ acc, float* __restrict__ out)
{
    const float LOG2E   = 1.4426950408889634f;
    const float LOG_2PI = 1.8378770664093453f;
    __shared__ float red[4];
    int wv = threadIdx.x >> 6, d = threadIdx.x & 63;
    int j = blockIdx.x * 4 + wv;
    int idx = j * D + d;
    acc[idx] = 0.0f;
    float lv = zlv[idx];
    float mu = zm[idx];
    float zz = zs[idx];
    float is = exp2fast(-LOG2E * lv);            // e^{-lv}
    float h  = -0.5f * LOG2E * is;
    float cv = -0.5f * LOG2E * (lv + LOG_2PI);
    float g  = -2.0f * mu * h;
    float q  = fmaf(mu * mu, h, cv);
    pack4[idx] = make_float4(h, g, q, 0.0f);
    Wt[j * 128 + d]      = f2bf(h);
    Wt[j * 128 + 64 + d] = f2bf(g);
    Zx[j * 128 + d]      = f2bf(zz * zz);
    Zx[j * 128 + 64 + d] = f2bf(zz);

    float qs = q, ks = kl[idx];
#pragma unroll
    for (int off = 32; off; off >>= 1) {
        qs += __shfl_xor(qs, off);
        ks += __shfl_xor(ks, off);
    }
    if (d == 0) { QQ[j] = qs; red[wv] = ks; }
    __syncthreads();
    if (threadIdx.x == 0)
        atomicAdd(out, red[0] + red[1] + red[2] + red[3]);  // kl_loss
}

// ---------------------------------------------------------------------------
// Role A (main), register-resident params: wave holds 16 j's (h,g,q) as 8
// packed v2f pairs (loaded once from pack4), sweeps 32 i's. Inner loop per i:
// one 4B z load + 16 pk_fma + 16 exp2 + 8 pk_add + 1 atomic. Lanes own d.
// gw in [0,8192): jc = gw & 127 (16-j chunk), i0 = (gw>>7)*32.
// ---------------------------------------------------------------------------
static __device__ __forceinline__ void role_main(
    int gw, const float* __restrict__ z, const float4* __restrict__ pack4,
    float* __restrict__ acc)
{
    int lane = threadIdx.x & 63;
    int jc   = gw & 127;
    int i0   = (gw >> 7) * 32;

    // setup: 16 float4 loads -> 8 j-pair param sets (register-resident)
    const float4* P = pack4 + (size_t)jc * 16 * 64 + lane;
    v2f hp[8], gp[8], qp[8];
#pragma unroll
    for (int r = 0; r < 8; ++r) {
        float4 p0 = P[(2 * r) * 64];
        float4 p1 = P[(2 * r + 1) * 64];
        hp[r] = (v2f){p0.x, p1.x};
        gp[r] = (v2f){p0.y, p1.y};
        qp[r] = (v2f){p0.z, p1.z};
    }

    const float* zcol = z + lane;
#pragma unroll 4
    for (int i = i0; i < i0 + 32; ++i) {
        float zv  = zcol[(size_t)i * 64];
        float zv2 = zv * zv;
        v2f zp  = (v2f){zv, zv};
        v2f zp2 = (v2f){zv2, zv2};
        v2f sp  = (v2f){0.0f, 0.0f};
#pragma unroll
        for (int r = 0; r < 8; ++r) {
            v2f arg = zp2 * hp[r] + (zp * gp[r] + qp[r]);   // 2x v_pk_fma_f32
            v2f e;
            e.x = exp2fast(arg.x);
            e.y = exp2fast(arg.y);
            sp += e;                                        // v_pk_add_f32
        }
        atomicAdd(&acc[(size_t)i * 64 + lane], sp.x + sp.y);
    }
}

// ---------------------------------------------------------------------------
// Role B (lse): s2[i][j] = QQ_j + sum_k Zx[i][k]*Wt[j][k] via 16x16x32 bf16
// MFMA, row-LSE over j fused in epilogue. One wave = 16-i block x 128-j chunk.
// C/D: col = lane&15 (j), row = (lane>>4)*4 + reg (i)  [m89-verified].
// ---------------------------------------------------------------------------
static __device__ __forceinline__ void role_lse(
    int lw, const unsigned short* __restrict__ Zx,
    const unsigned short* __restrict__ Wt, const float* __restrict__ QQ,
    float* __restrict__ wsM, float* __restrict__ wsL)
{
    int lane  = threadIdx.x & 63;
    int i0    = (lw >> 4) * 16;
    int chunk = lw & 15;               // 0..15
    int jbase = chunk * 128;
    int r16 = lane & 15, kg = lane >> 4;

    const bf16x8* Za = (const bf16x8*)(Zx + (size_t)(i0 + r16) * 128 + kg * 8);
    bf16x8 a[4];
#pragma unroll
    for (int s = 0; s < 4; ++s) a[s] = Za[s * 4];   // stride 32 bf16 per K-step

    float m[4], l[4];
#pragma unroll
    for (int r = 0; r < 4; ++r) { m[r] = -3.0e38f; l[r] = 0.0f; }

    for (int t = 0; t < 8; ++t) {
        int j = jbase + t * 16 + r16;
        const bf16x8* Wb = (const bf16x8*)(Wt + (size_t)j * 128 + kg * 8);
        f32x4 c = (f32x4){0.0f, 0.0f, 0.0f, 0.0f};
#pragma unroll
        for (int s = 0; s < 4; ++s)
            c = __builtin_amdgcn_mfma_f32_16x16x32_bf16(a[s], Wb[s * 4], c, 0, 0, 0);
        float qq = QQ[j];
#pragma unroll
        for (int r = 0; r < 4; ++r) {
            float val = c[r] + qq;
            float delta = val - m[r];
            float e = exp2fast(-fabsf(delta));
            l[r] = (delta <= 0.0f) ? (l[r] + e) : fmaf(l[r], e, 1.0f);
            m[r] = fmaxf(m[r], val);
        }
    }
#pragma unroll
    for (int off = 8; off; off >>= 1) {
#pragma unroll
        for (int r = 0; r < 4; ++r) {
            float m2 = __shfl_xor(m[r], off);
            float l2 = __shfl_xor(l[r], off);
            float M  = fmaxf(m[r], m2);
            l[r] = fmaf(l[r], exp2fast(m[r] - M), l2 * exp2fast(m2 - M));
            m[r] = M;
        }
    }
    if (r16 == 0) {
#pragma unroll
        for (int r = 0; r < 4; ++r) {
            int i = i0 + kg * 4 + r;
            wsM[i * NC2 + chunk] = m[r];
            wsL[i * NC2 + chunk] = l[r];
        }
    }
}

// ---------------------------------------------------------------------------
// Kernel 2: 2560 UNIFORM 256-thread blocks: every 5th block runs 4 lse waves
// (512 blocks x 4 = 2048 lse waves); the rest run 4 main waves each
// (2048 blocks x 4 = 8192 main waves). A main block's 4 waves share the same
// i-range (consecutive gw => same gw>>7 mostly) for z L1 reuse. lse blocks
// are short and get backfilled by queued main blocks.
// ---------------------------------------------------------------------------
__global__ __launch_bounds__(256) void k_mega(
    const float* __restrict__ z, const float4* __restrict__ pack4,
    float* __restrict__ acc, const unsigned short* __restrict__ Zx,
    const unsigned short* __restrict__ Wt, const float* __restrict__ QQ,
    float* __restrict__ wsM, float* __restrict__ wsL)
{
    int wv = threadIdx.x >> 6;
    unsigned bq = blockIdx.x / 5, br = blockIdx.x % 5;
    if (br == 4)
        role_lse(bq * 4 + wv, Zx, Wt, QQ, wsM, wsL);       // 0..2047
    else
        role_main((bq * 4 + br) * 4 + wv, z, pack4, acc);  // 0..8191
}

// ---------------------------------------------------------------------------
// Kernel 3: per-i finalization, one wave per i.
// ---------------------------------------------------------------------------
__global__ __launch_bounds__(256) void k_fin(
    const float* __restrict__ acc, const float* __restrict__ wsM,
    const float* __restrict__ wsL, float* __restrict__ out)
{
    const float LN2 = 0.6931471805599453f;
    __shared__ float red[4];
    int lane = threadIdx.x & 63;
    int wv   = threadIdx.x >> 6;
    int i    = blockIdx.x * 4 + wv;

    float lqp2 = log2fast(acc[i * D + lane]);
#pragma unroll
    for (int off = 32; off; off >>= 1) lqp2 += __shfl_xor(lqp2, off);

    float m = -3.0e38f, l = 0.0f;
    if (lane < NC2) { m = wsM[i * NC2 + lane]; l = wsL[i * NC2 + lane]; }
#pragma unroll
    for (int off = 32; off; off >>= 1) {
        float m2 = __shfl_xor(m, off);
        float l2 = __shfl_xor(l, off);
        float M  = fmaxf(m, m2);
        l = fmaf(l, exp2fast(m - M), l2 * exp2fast(m2 - M));
        m = M;
    }

    if (lane == 0)
        red[wv] = (m + log2fast(l) - lqp2) * LN2;
    __syncthreads();
    if (threadIdx.x == 0)
        atomicAdd(out, (red[0] + red[1] + red[2] + red[3]) * (5.0f / 2048.0f));
}

// ---------------------------------------------------------------------------
extern "C" void kernel_launch(void* const* d_in, const int* in_sizes, int n_in,
                              void* d_out, int out_size, void* d_ws, size_t ws_size,
                              hipStream_t stream)
{
    const float* kl  = (const float*)d_in[0];
    const float* zm  = (const float*)d_in[1];
    const float* zlv = (const float*)d_in[2];
    const float* zs  = (const float*)d_in[3];
    float* out = (float*)d_out;
    float* ws  = (float*)d_ws;

    // workspace layout (floats)
    float4*         pack4 = (float4*)ws;                         // 4*B*D
    unsigned short* Zx    = (unsigned short*)(ws + 4 * B * D);   // B*128 u16
    unsigned short* Wt    = (unsigned short*)(ws + 4 * B * D + (B * 128) / 2);
    float*          QQ    = ws + 4 * B * D + B * 128;            // B
    float*          wsM   = QQ + B;                              // B*NC2
    float*          wsL   = wsM + (size_t)B * NC2;               // B*NC2
    float*          acc   = wsL + (size_t)B * NC2;               // B*D

    hipMemsetAsync(d_out, 0, sizeof(float), stream);
    k_pre<<<B / 4, 256, 0, stream>>>(kl, zm, zlv, zs, pack4, Zx, Wt, QQ, acc, out);
    k_mega<<<2560, 256, 0, stream>>>(zs, pack4, acc, Zx, Wt, QQ, wsM, wsL);
    k_fin<<<B / 4, 256, 0, stream>>>(acc, wsM, wsL, out);
}

// Round 10
// 62.893 us; speedup vs baseline: 2.1380x; 2.1380x over previous
//
#include <hip/hip_runtime.h>
#include <math.h>

#define B 2048
#define D 64
#define IT 8            // i-rows per main wave (r5-proven)
#define NCH 32          // j-chunks for main role
#define CJ (B / NCH)    // 64
#define NC2 16          // j-chunks for the MFMA/LSE role
#define MAIN_BLOCKS 2048
#define LSE_BLOCKS 512

typedef float v2f  __attribute__((ext_vector_type(2)));
typedef short bf16x8 __attribute__((ext_vector_type(8)));
typedef float f32x4  __attribute__((ext_vector_type(4)));

static __device__ __forceinline__ float exp2fast(float x) { return __builtin_amdgcn_exp2f(x); }
static __device__ __forceinline__ float log2fast(float x) { return __builtin_amdgcn_logf(x); }
static __device__ __forceinline__ unsigned short f2bf(float x) {
    unsigned u = __float_as_uint(x);
    u += 0x7fff + ((u >> 16) & 1);          // RNE; inputs are finite
    return (unsigned short)(u >> 16);
}

// ---------------------------------------------------------------------------
// Kernel 1: per-(j,d) constants (log2 units):  lp2 = h*z^2 + g*z + q
// Outputs: pack4 (fp32), Zx/Wt (bf16 MFMA operands), QQ[j]=sum_d q,
// acc zeroed, kl block-partials -> ws_klp[bid] (plain store), out zeroed.
// ---------------------------------------------------------------------------
__global__ __launch_bounds__(256) void k_pre(
    const float* __restrict__ kl, const float* __restrict__ zm,
    const float* __restrict__ zlv, const float* __restrict__ zs,
    float4* __restrict__ pack4, unsigned short* __restrict__ Zx,
    unsigned short* __restrict__ Wt, float* __restrict__ QQ,
    float* __restrict__ acc, float* __restrict__ klp, float* __restrict__ out)
{
    const float LOG2E   = 1.4426950408889634f;
    const float LOG_2PI = 1.8378770664093453f;
    __shared__ float red[4];
    int wv = threadIdx.x >> 6, d = threadIdx.x & 63;
    int j = blockIdx.x * 4 + wv;
    int idx = j * D + d;
    acc[idx] = 0.0f;
    float lv = zlv[idx];
    float mu = zm[idx];
    float zz = zs[idx];
    float is = exp2fast(-LOG2E * lv);            // e^{-lv}
    float h  = -0.5f * LOG2E * is;
    float cv = -0.5f * LOG2E * (lv + LOG_2PI);
    float g  = -2.0f * mu * h;
    float q  = fmaf(mu * mu, h, cv);
    pack4[idx] = make_float4(h, g, q, 0.0f);
    Wt[j * 128 + d]      = f2bf(h);
    Wt[j * 128 + 64 + d] = f2bf(g);
    Zx[j * 128 + d]      = f2bf(zz * zz);
    Zx[j * 128 + 64 + d] = f2bf(zz);

    float qs = q, ks = kl[idx];
#pragma unroll
    for (int off = 32; off; off >>= 1) {
        qs += __shfl_xor(qs, off);
        ks += __shfl_xor(ks, off);
    }
    if (d == 0) { QQ[j] = qs; red[wv] = ks; }
    __syncthreads();
    if (threadIdx.x == 0) {
        klp[blockIdx.x] = red[0] + red[1] + red[2] + red[3];  // kl partial
        if (blockIdx.x == 0) out[0] = 0.0f;                   // zero output
    }
}

// ---------------------------------------------------------------------------
// Role A (main) — r5-proven: acc[i][d] += sum_j 2^(h z^2 + g z + q).
// Wave = IT=8 rows i (4 float2 pairs), one 64-j chunk, lanes own d.
// ---------------------------------------------------------------------------
static __device__ __forceinline__ void role_main(
    int chunk, int igroup, const float* __restrict__ z,
    const float4* __restrict__ pack4, float* __restrict__ acc)
{
    int lane = threadIdx.x & 63;
    int i0   = igroup * IT;
    int j0   = chunk * CJ;

    v2f zrp[IT / 2], zr2p[IT / 2], ap[IT / 2];
#pragma unroll
    for (int kp = 0; kp < IT / 2; ++kp) {
        float za = z[(i0 + 2 * kp) * D + lane];
        float zb = z[(i0 + 2 * kp + 1) * D + lane];
        zrp[kp]  = (v2f){za, zb};
        zr2p[kp] = (v2f){za * za, zb * zb};
        ap[kp]   = (v2f){0.0f, 0.0f};
    }

#pragma unroll 2
    for (int j = j0; j < j0 + CJ; ++j) {
        float4 p = pack4[j * D + lane];
        v2f hh = (v2f){p.x, p.x};
        v2f gg = (v2f){p.y, p.y};
        v2f qq = (v2f){p.z, p.z};
#pragma unroll
        for (int kp = 0; kp < IT / 2; ++kp) {
            v2f arg = zr2p[kp] * hh + (zrp[kp] * gg + qq);  // 2x v_pk_fma_f32
            v2f e;
            e.x = exp2fast(arg.x);
            e.y = exp2fast(arg.y);
            ap[kp] += e;                                    // v_pk_add_f32
        }
    }
#pragma unroll
    for (int kp = 0; kp < IT / 2; ++kp) {
        atomicAdd(&acc[(i0 + 2 * kp) * D + lane], ap[kp].x);
        atomicAdd(&acc[(i0 + 2 * kp + 1) * D + lane], ap[kp].y);
    }
}

// ---------------------------------------------------------------------------
// Role B (lse): s2[i][j] = QQ_j + sum_k Zx[i][k]*Wt[j][k] via 16x16x32 bf16
// MFMA, row-LSE over j fused in epilogue. One wave = 16-i block x 128-j chunk.
// C/D: col = lane&15 (j), row = (lane>>4)*4 + reg (i)  [m89-verified].
// ---------------------------------------------------------------------------
static __device__ __forceinline__ void role_lse(
    int lw, const unsigned short* __restrict__ Zx,
    const unsigned short* __restrict__ Wt, const float* __restrict__ QQ,
    float* __restrict__ wsM, float* __restrict__ wsL)
{
    int lane  = threadIdx.x & 63;
    int i0    = (lw >> 4) * 16;
    int chunk = lw & 15;               // 0..15
    int jbase = chunk * 128;
    int r16 = lane & 15, kg = lane >> 4;

    const bf16x8* Za = (const bf16x8*)(Zx + (size_t)(i0 + r16) * 128 + kg * 8);
    bf16x8 a[4];
#pragma unroll
    for (int s = 0; s < 4; ++s) a[s] = Za[s * 4];   // stride 32 bf16 per K-step

    float m[4], l[4];
#pragma unroll
    for (int r = 0; r < 4; ++r) { m[r] = -3.0e38f; l[r] = 0.0f; }

    for (int t = 0; t < 8; ++t) {
        int j = jbase + t * 16 + r16;
        const bf16x8* Wb = (const bf16x8*)(Wt + (size_t)j * 128 + kg * 8);
        f32x4 c = (f32x4){0.0f, 0.0f, 0.0f, 0.0f};
#pragma unroll
        for (int s = 0; s < 4; ++s)
            c = __builtin_amdgcn_mfma_f32_16x16x32_bf16(a[s], Wb[s * 4], c, 0, 0, 0);
        float qq = QQ[j];
#pragma unroll
        for (int r = 0; r < 4; ++r) {
            float val = c[r] + qq;
            float delta = val - m[r];
            float e = exp2fast(-fabsf(delta));
            l[r] = (delta <= 0.0f) ? (l[r] + e) : fmaf(l[r], e, 1.0f);
            m[r] = fmaxf(m[r], val);
        }
    }
#pragma unroll
    for (int off = 8; off; off >>= 1) {
#pragma unroll
        for (int r = 0; r < 4; ++r) {
            float m2 = __shfl_xor(m[r], off);
            float l2 = __shfl_xor(l[r], off);
            float M  = fmaxf(m[r], m2);
            l[r] = fmaf(l[r], exp2fast(m[r] - M), l2 * exp2fast(m2 - M));
            m[r] = M;
        }
    }
    if (r16 == 0) {
#pragma unroll
        for (int r = 0; r < 4; ++r) {
            int i = i0 + kg * 4 + r;
            wsM[i * NC2 + chunk] = m[r];
            wsL[i * NC2 + chunk] = l[r];
        }
    }
}

// ---------------------------------------------------------------------------
// Kernel 2: blocks [0,2048) = main role, identical to r5's proven k_main
// (wid = bid*4+wv; chunk = wid&31; igroup = wid>>5). Blocks [2048,2560) =
// lse role, APPENDED AT THE GRID TAIL so the 512 short LSE blocks launch
// only as main blocks retire — they fill the ragged tail instead of
// stealing slots at t=0 (r7's mistake).
// ---------------------------------------------------------------------------
__global__ __launch_bounds__(256) void k_mega(
    const float* __restrict__ z, const float4* __restrict__ pack4,
    float* __restrict__ acc, const unsigned short* __restrict__ Zx,
    const unsigned short* __restrict__ Wt, const float* __restrict__ QQ,
    float* __restrict__ wsM, float* __restrict__ wsL)
{
    int wv  = threadIdx.x >> 6;
    int bid = blockIdx.x;
    if (bid < MAIN_BLOCKS) {
        int wid = bid * 4 + wv;
        role_main(wid & (NCH - 1), wid >> 5, z, pack4, acc);
    } else {
        int lw = (bid - MAIN_BLOCKS) * 4 + wv;   // 0..2047
        role_lse(lw, Zx, Wt, QQ, wsM, wsL);
    }
}

// ---------------------------------------------------------------------------
// Kernel 3: per-i finalization, one wave per i; folds the kl partial from
// k_pre (same 512-block grid) into its single atomic per block.
// ---------------------------------------------------------------------------
__global__ __launch_bounds__(256) void k_fin(
    const float* __restrict__ acc, const float* __restrict__ wsM,
    const float* __restrict__ wsL, const float* __restrict__ klp,
    float* __restrict__ out)
{
    const float LN2 = 0.6931471805599453f;
    __shared__ float red[4];
    int lane = threadIdx.x & 63;
    int wv   = threadIdx.x >> 6;
    int i    = blockIdx.x * 4 + wv;

    float lqp2 = log2fast(acc[i * D + lane]);
#pragma unroll
    for (int off = 32; off; off >>= 1) lqp2 += __shfl_xor(lqp2, off);

    float m = -3.0e38f, l = 0.0f;
    if (lane < NC2) { m = wsM[i * NC2 + lane]; l = wsL[i * NC2 + lane]; }
#pragma unroll
    for (int off = 32; off; off >>= 1) {
        float m2 = __shfl_xor(m, off);
        float l2 = __shfl_xor(l, off);
        float M  = fmaxf(m, m2);
        l = fmaf(l, exp2fast(m - M), l2 * exp2fast(m2 - M));
        m = M;
    }

    if (lane == 0)
        red[wv] = (m + log2fast(l) - lqp2) * LN2;
    __syncthreads();
    if (threadIdx.x == 0)
        atomicAdd(out, (red[0] + red[1] + red[2] + red[3]) * (5.0f / 2048.0f)
                       + klp[blockIdx.x]);
}

// ---------------------------------------------------------------------------
extern "C" void kernel_launch(void* const* d_in, const int* in_sizes, int n_in,
                              void* d_out, int out_size, void* d_ws, size_t ws_size,
                              hipStream_t stream)
{
    const float* kl  = (const float*)d_in[0];
    const float* zm  = (const float*)d_in[1];
    const float* zlv = (const float*)d_in[2];
    const float* zs  = (const float*)d_in[3];
    float* out = (float*)d_out;
    float* ws  = (float*)d_ws;

    // workspace layout (floats)
    float4*         pack4 = (float4*)ws;                         // 4*B*D
    unsigned short* Zx    = (unsigned short*)(ws + 4 * B * D);   // B*128 u16
    unsigned short* Wt    = (unsigned short*)(ws + 4 * B * D + (B * 128) / 2);
    float*          QQ    = ws + 4 * B * D + B * 128;            // B
    float*          wsM   = QQ + B;                              // B*NC2
    float*          wsL   = wsM + (size_t)B * NC2;               // B*NC2
    float*          acc   = wsL + (size_t)B * NC2;               // B*D
    float*          klp   = acc + (size_t)B * D;                 // 512

    k_pre<<<B / 4, 256, 0, stream>>>(kl, zm, zlv, zs, pack4, Zx, Wt, QQ, acc, klp, out);
    k_mega<<<MAIN_BLOCKS + LSE_BLOCKS, 256, 0, stream>>>(zs, pack4, acc, Zx, Wt, QQ, wsM, wsL);
    k_fin<<<B / 4, 256, 0, stream>>>(acc, wsM, wsL, klp, out);
}

// Round 11
// 57.039 us; speedup vs baseline: 2.3574x; 1.1026x over previous
//
#include <hip/hip_runtime.h>
#include <math.h>

#define B 2048
#define D 64
#define IT 8            // i-rows per main wave (r5-proven)
#define NCH 32          // j-chunks for main role
#define CJ (B / NCH)    // 64
#define NC2 16          // j-chunks for the MFMA/LSE role
#define MAIN_BLOCKS 2048
#define LSE_BLOCKS 512

typedef float v2f  __attribute__((ext_vector_type(2)));
typedef short bf16x8 __attribute__((ext_vector_type(8)));
typedef float f32x4  __attribute__((ext_vector_type(4)));

static __device__ __forceinline__ float exp2fast(float x) { return __builtin_amdgcn_exp2f(x); }
static __device__ __forceinline__ float log2fast(float x) { return __builtin_amdgcn_logf(x); }
static __device__ __forceinline__ unsigned short f2bf(float x) {
    unsigned u = __float_as_uint(x);
    u += 0x7fff + ((u >> 16) & 1);          // RNE; inputs are finite
    return (unsigned short)(u >> 16);
}

// ---------------------------------------------------------------------------
// Kernel 1: per-(j,d) constants (log2 units):  lp2 = h*z^2 + g*z + q
// Outputs: pack4 (fp32), Zx/Wt (bf16 MFMA operands), QQ[j]=sum_d q,
// acc zeroed, kl block-partials -> klp[bid] (plain store), out zeroed.
// ---------------------------------------------------------------------------
__global__ __launch_bounds__(256) void k_pre(
    const float* __restrict__ kl, const float* __restrict__ zm,
    const float* __restrict__ zlv, const float* __restrict__ zs,
    float4* __restrict__ pack4, unsigned short* __restrict__ Zx,
    unsigned short* __restrict__ Wt, float* __restrict__ QQ,
    float* __restrict__ acc, float* __restrict__ klp, float* __restrict__ out)
{
    const float LOG2E   = 1.4426950408889634f;
    const float LOG_2PI = 1.8378770664093453f;
    __shared__ float red[4];
    int wv = threadIdx.x >> 6, d = threadIdx.x & 63;
    int j = blockIdx.x * 4 + wv;
    int idx = j * D + d;
    acc[idx] = 0.0f;
    float lv = zlv[idx];
    float mu = zm[idx];
    float zz = zs[idx];
    float is = exp2fast(-LOG2E * lv);            // e^{-lv}
    float h  = -0.5f * LOG2E * is;
    float cv = -0.5f * LOG2E * (lv + LOG_2PI);
    float g  = -2.0f * mu * h;
    float q  = fmaf(mu * mu, h, cv);
    pack4[idx] = make_float4(h, g, q, 0.0f);
    Wt[j * 128 + d]      = f2bf(h);
    Wt[j * 128 + 64 + d] = f2bf(g);
    Zx[j * 128 + d]      = f2bf(zz * zz);
    Zx[j * 128 + 64 + d] = f2bf(zz);

    float qs = q, ks = kl[idx];
#pragma unroll
    for (int off = 32; off; off >>= 1) {
        qs += __shfl_xor(qs, off);
        ks += __shfl_xor(ks, off);
    }
    if (d == 0) { QQ[j] = qs; red[wv] = ks; }
    __syncthreads();
    if (threadIdx.x == 0) {
        klp[blockIdx.x] = red[0] + red[1] + red[2] + red[3];  // kl partial
        if (blockIdx.x == 0) out[0] = 0.0f;                   // zero output
    }
}

// ---------------------------------------------------------------------------
// Role A (main): acc[i][d] += sum_j 2^(h z^2 + g z + q).
// Wave = IT=8 rows i (4 float2 pairs), one 64-j chunk, lanes own d.
// unroll 4 => up to 4 pack4 loads in flight (covers ~200cy L2 latency).
// ---------------------------------------------------------------------------
static __device__ __forceinline__ void role_main(
    int chunk, int igroup, const float* __restrict__ z,
    const float4* __restrict__ pack4, float* __restrict__ acc)
{
    int lane = threadIdx.x & 63;
    int i0   = igroup * IT;
    int j0   = chunk * CJ;

    v2f zrp[IT / 2], zr2p[IT / 2], ap[IT / 2];
#pragma unroll
    for (int kp = 0; kp < IT / 2; ++kp) {
        float za = z[(i0 + 2 * kp) * D + lane];
        float zb = z[(i0 + 2 * kp + 1) * D + lane];
        zrp[kp]  = (v2f){za, zb};
        zr2p[kp] = (v2f){za * za, zb * zb};
        ap[kp]   = (v2f){0.0f, 0.0f};
    }

#pragma unroll 4
    for (int j = j0; j < j0 + CJ; ++j) {
        float4 p = pack4[j * D + lane];
        v2f hh = (v2f){p.x, p.x};
        v2f gg = (v2f){p.y, p.y};
        v2f qq = (v2f){p.z, p.z};
#pragma unroll
        for (int kp = 0; kp < IT / 2; ++kp) {
            v2f arg = zr2p[kp] * hh + (zrp[kp] * gg + qq);  // 2x v_pk_fma_f32
            v2f e;
            e.x = exp2fast(arg.x);
            e.y = exp2fast(arg.y);
            ap[kp] += e;                                    // v_pk_add_f32
        }
    }
#pragma unroll
    for (int kp = 0; kp < IT / 2; ++kp) {
        atomicAdd(&acc[(i0 + 2 * kp) * D + lane], ap[kp].x);
        atomicAdd(&acc[(i0 + 2 * kp + 1) * D + lane], ap[kp].y);
    }
}

// ---------------------------------------------------------------------------
// Role B (lse): s2[i][j] = QQ_j + sum_k Zx[i][k]*Wt[j][k] via 16x16x32 bf16
// MFMA, row-LSE over j fused in epilogue. One wave = 16-i block x 128-j chunk.
// C/D: col = lane&15 (j), row = (lane>>4)*4 + reg (i)  [m89-verified].
// ---------------------------------------------------------------------------
static __device__ __forceinline__ void role_lse(
    int lw, const unsigned short* __restrict__ Zx,
    const unsigned short* __restrict__ Wt, const float* __restrict__ QQ,
    float* __restrict__ wsM, float* __restrict__ wsL)
{
    int lane  = threadIdx.x & 63;
    int i0    = (lw >> 4) * 16;
    int chunk = lw & 15;               // 0..15
    int jbase = chunk * 128;
    int r16 = lane & 15, kg = lane >> 4;

    const bf16x8* Za = (const bf16x8*)(Zx + (size_t)(i0 + r16) * 128 + kg * 8);
    bf16x8 a[4];
#pragma unroll
    for (int s = 0; s < 4; ++s) a[s] = Za[s * 4];   // stride 32 bf16 per K-step

    float m[4], l[4];
#pragma unroll
    for (int r = 0; r < 4; ++r) { m[r] = -3.0e38f; l[r] = 0.0f; }

    for (int t = 0; t < 8; ++t) {
        int j = jbase + t * 16 + r16;
        const bf16x8* Wb = (const bf16x8*)(Wt + (size_t)j * 128 + kg * 8);
        f32x4 c = (f32x4){0.0f, 0.0f, 0.0f, 0.0f};
#pragma unroll
        for (int s = 0; s < 4; ++s)
            c = __builtin_amdgcn_mfma_f32_16x16x32_bf16(a[s], Wb[s * 4], c, 0, 0, 0);
        float qq = QQ[j];
#pragma unroll
        for (int r = 0; r < 4; ++r) {
            float val = c[r] + qq;
            float delta = val - m[r];
            float e = exp2fast(-fabsf(delta));
            l[r] = (delta <= 0.0f) ? (l[r] + e) : fmaf(l[r], e, 1.0f);
            m[r] = fmaxf(m[r], val);
        }
    }
#pragma unroll
    for (int off = 8; off; off >>= 1) {
#pragma unroll
        for (int r = 0; r < 4; ++r) {
            float m2 = __shfl_xor(m[r], off);
            float l2 = __shfl_xor(l[r], off);
            float M  = fmaxf(m[r], m2);
            l[r] = fmaf(l[r], exp2fast(m[r] - M), l2 * exp2fast(m2 - M));
            m[r] = M;
        }
    }
    if (r16 == 0) {
#pragma unroll
        for (int r = 0; r < 4; ++r) {
            int i = i0 + kg * 4 + r;
            wsM[i * NC2 + chunk] = m[r];
            wsL[i * NC2 + chunk] = l[r];
        }
    }
}

// ---------------------------------------------------------------------------
// Kernel 2: blocks [0,2048) = main role. NEW mapping: chunk = bid&31 so all
// 4 waves of a block share ONE 64KB pack4 window (L1 reuse), and all 64
// blocks of a chunk share an XCD (bid%8 const for bid≡c mod 32) so the
// window is pinned in one L2 (4 chunks/XCD = 256KB in 4MB).
// igroup = (bid>>5)*4 + wv covers 0..255 per chunk.
// Blocks [2048,2560) = lse role at the grid tail.
// ---------------------------------------------------------------------------
__global__ __launch_bounds__(256) void k_mega(
    const float* __restrict__ z, const float4* __restrict__ pack4,
    float* __restrict__ acc, const unsigned short* __restrict__ Zx,
    const unsigned short* __restrict__ Wt, const float* __restrict__ QQ,
    float* __restrict__ wsM, float* __restrict__ wsL)
{
    int wv  = threadIdx.x >> 6;
    int bid = blockIdx.x;
    if (bid < MAIN_BLOCKS) {
        role_main(bid & (NCH - 1), (bid >> 5) * 4 + wv, z, pack4, acc);
    } else {
        int lw = (bid - MAIN_BLOCKS) * 4 + wv;   // 0..2047
        role_lse(lw, Zx, Wt, QQ, wsM, wsL);
    }
}

// ---------------------------------------------------------------------------
// Kernel 3: per-i finalization, one wave per i; folds the kl partial from
// k_pre (same 512-block grid) into its single atomic per block.
// ---------------------------------------------------------------------------
__global__ __launch_bounds__(256) void k_fin(
    const float* __restrict__ acc, const float* __restrict__ wsM,
    const float* __restrict__ wsL, const float* __restrict__ klp,
    float* __restrict__ out)
{
    const float LN2 = 0.6931471805599453f;
    __shared__ float red[4];
    int lane = threadIdx.x & 63;
    int wv   = threadIdx.x >> 6;
    int i    = blockIdx.x * 4 + wv;

    float lqp2 = log2fast(acc[i * D + lane]);
#pragma unroll
    for (int off = 32; off; off >>= 1) lqp2 += __shfl_xor(lqp2, off);

    float m = -3.0e38f, l = 0.0f;
    if (lane < NC2) { m = wsM[i * NC2 + lane]; l = wsL[i * NC2 + lane]; }
#pragma unroll
    for (int off = 32; off; off >>= 1) {
        float m2 = __shfl_xor(m, off);
        float l2 = __shfl_xor(l, off);
        float M  = fmaxf(m, m2);
        l = fmaf(l, exp2fast(m - M), l2 * exp2fast(m2 - M));
        m = M;
    }

    if (lane == 0)
        red[wv] = (m + log2fast(l) - lqp2) * LN2;
    __syncthreads();
    if (threadIdx.x == 0)
        atomicAdd(out, (red[0] + red[1] + red[2] + red[3]) * (5.0f / 2048.0f)
                       + klp[blockIdx.x]);
}

// ---------------------------------------------------------------------------
extern "C" void kernel_launch(void* const* d_in, const int* in_sizes, int n_in,
                              void* d_out, int out_size, void* d_ws, size_t ws_size,
                              hipStream_t stream)
{
    const float* kl  = (const float*)d_in[0];
    const float* zm  = (const float*)d_in[1];
    const float* zlv = (const float*)d_in[2];
    const float* zs  = (const float*)d_in[3];
    float* out = (float*)d_out;
    float* ws  = (float*)d_ws;

    // workspace layout (floats)
    float4*         pack4 = (float4*)ws;                         // 4*B*D
    unsigned short* Zx    = (unsigned short*)(ws + 4 * B * D);   // B*128 u16
    unsigned short* Wt    = (unsigned short*)(ws + 4 * B * D + (B * 128) / 2);
    float*          QQ    = ws + 4 * B * D + B * 128;            // B
    float*          wsM   = QQ + B;                              // B*NC2
    float*          wsL   = wsM + (size_t)B * NC2;               // B*NC2
    float*          acc   = wsL + (size_t)B * NC2;               // B*D
    float*          klp   = acc + (size_t)B * D;                 // 512

    k_pre<<<B / 4, 256, 0, stream>>>(kl, zm, zlv, zs, pack4, Zx, Wt, QQ, acc, klp, out);
    k_mega<<<MAIN_BLOCKS + LSE_BLOCKS, 256, 0, stream>>>(zs, pack4, acc, Zx, Wt, QQ, wsM, wsL);
    k_fin<<<B / 4, 256, 0, stream>>>(acc, wsM, wsL, klp, out);
}